// Round 3
// baseline (14403.905 us; speedup 1.0000x reference)
//
#include <hip/hip_runtime.h>
#include <hip/hip_cooperative_groups.h>
#include <math.h>

namespace cg = cooperative_groups;

#define HDIM 1024
#define BDIM 256
#define TSTEPS 64
#define TH3 3072

__device__ __forceinline__ float sigmoidf_(float x) {
    return 1.0f / (1.0f + __expf(-x));
}

// ===========================================================================
// Persistent cooperative kernel. 256 blocks (1/CU) x 512 threads (8 waves).
// Dynamic LDS 128 KB: WA[1024][16] (cols of [W_out|W_r]) + WB[1024][16]
// (cols of W_k, layout [k][jj*4 + chunk], jj=0..3, chunk=z/r/h, col3 pad).
// Thread (row = tid&255, half = tid>>8):
//   phase A: C[row][16b+8h .. +7] = h_row . WA  (relu->outb,dout | mh+bias)
//   phase B: mx for j = 4b+2h+{0,1} x 3 chunks, fused GRU gates -> h[row][j]
// Weights loaded to LDS ONCE; 64 steps of 2 grid.sync() each.
// ===========================================================================
__global__ __launch_bounds__(512, 1) void decoder_persistent(
    const float* __restrict__ x,
    const float* __restrict__ W_fs, const float* __restrict__ b_fs,
    const float* __restrict__ W_out, const float* __restrict__ b_out,
    const float* __restrict__ W_k,  const float* __restrict__ W_r,
    const float* __restrict__ b_gru,
    float* __restrict__ dout,
    float* __restrict__ h, float* __restrict__ outb, float* __restrict__ mh)
{
    extern __shared__ float lds[];
    float* WA = lds;                 // [1024][16]
    float* WB = lds + 1024 * 16;     // [1024][16] (12 used + pad)

    cg::grid_group grid = cg::this_grid();

    const int b    = blockIdx.x;
    const int tid  = threadIdx.x;
    const int row  = tid & 255;
    const int half = tid >> 8;       // 0 or 1

    // ---- one-time LDS weight fill ----
    {
        const float* Wsrc;
        int ldw;
        if (b < 64) { Wsrc = W_out + 16 * b;        ldw = HDIM; }
        else        { Wsrc = W_r  + 16 * (b - 64);  ldw = TH3;  }
        for (int i = tid; i < 4096; i += 512) {
            const int k = i >> 2, cq = (i & 3) << 2;
            const float4 v = *(const float4*)(Wsrc + (size_t)k * ldw + cq);
            *(float4*)(WA + k * 16 + cq) = v;
        }
        for (int i = tid; i < 4096; i += 512) {
            const int k = i >> 2, jj = i & 3;
            const size_t base = (size_t)k * TH3 + 4 * b + jj;
            const float vz = W_k[base];
            const float vr = W_k[base + 1024];
            const float vh = W_k[base + 2048];
            *(float4*)(WB + k * 16 + jj * 4) = make_float4(vz, vr, vh, 0.0f);
        }
    }

    // ---- biases into registers ----
    float biasA[8];
    {
        const float* bsrc = (b < 64) ? (b_out + 16 * b)
                                     : (b_gru + TH3 + 16 * (b - 64));
        const int c0 = 8 * half;
#pragma unroll
        for (int j = 0; j < 8; ++j) biasA[j] = bsrc[c0 + j];
    }
    float bz[2], br[2], bh[2];
#pragma unroll
    for (int q = 0; q < 2; ++q) {
        const int j = 4 * b + 2 * half + q;
        bz[q] = b_gru[j];
        br[q] = b_gru[HDIM + j];
        bh[q] = b_gru[2 * HDIM + j];
    }

    // ---- phase 0: h0 = tanh(x @ W_fs + b_fs), cols 4b+2h+{0,1} ----
    {
        float acc0 = 0.0f, acc1 = 0.0f;
        const int c = 4 * b + 2 * half;
        const float* xr = x + (size_t)row * HDIM;
        for (int k = 0; k < HDIM; k += 4) {
            const float4 a = *(const float4*)(xr + k);
#pragma unroll
            for (int kk = 0; kk < 4; ++kk) {
                const float2 w = *(const float2*)(W_fs + (size_t)(k + kk) * HDIM + c);
                const float av = (&a.x)[kk];
                acc0 = fmaf(av, w.x, acc0);
                acc1 = fmaf(av, w.y, acc1);
            }
        }
        h[(size_t)row * HDIM + c]     = tanhf(acc0 + b_fs[c]);
        h[(size_t)row * HDIM + c + 1] = tanhf(acc1 + b_fs[c + 1]);
    }
    grid.sync();

    // ---- recurrence ----
    for (int t = 0; t <= TSTEPS; ++t) {
        // ===== phase A: [out | mh] = h @ [W_out | W_r] =====
        {
            const float* A = h + (size_t)row * HDIM;
            float acc[8] = {};
            const float* wa = WA + 8 * half;
            float4 an = *(const float4*)(A);
            for (int k4 = 0; k4 < 256; ++k4) {
                const float4 ac = an;
                an = *(const float4*)(A + 4 * (k4 + 1));   // row<255 -> next row; row 255 -> outb[0]; value unused at k4=255
#pragma unroll
                for (int kk = 0; kk < 4; ++kk) {
                    const int k = 4 * k4 + kk;
                    const float av = (&ac.x)[kk];
                    const float4 w0 = *(const float4*)(wa + k * 16);
                    const float4 w1 = *(const float4*)(wa + k * 16 + 4);
                    acc[0] = fmaf(av, w0.x, acc[0]);
                    acc[1] = fmaf(av, w0.y, acc[1]);
                    acc[2] = fmaf(av, w0.z, acc[2]);
                    acc[3] = fmaf(av, w0.w, acc[3]);
                    acc[4] = fmaf(av, w1.x, acc[4]);
                    acc[5] = fmaf(av, w1.y, acc[5]);
                    acc[6] = fmaf(av, w1.z, acc[6]);
                    acc[7] = fmaf(av, w1.w, acc[7]);
                }
            }
            const int c0 = 16 * b + 8 * half;   // col in concat space (b<64) or +16*(b-64)... handled below
            if (b < 64) {
                float v[8];
#pragma unroll
                for (int j = 0; j < 8; ++j) v[j] = fmaxf(acc[j] + biasA[j], 0.0f);
                float4* o0 = (float4*)(outb + (size_t)row * HDIM + c0);
                o0[0] = make_float4(v[0], v[1], v[2], v[3]);
                o0[1] = make_float4(v[4], v[5], v[6], v[7]);
                if (t >= 1) {
                    float4* o1 = (float4*)(dout + (size_t)row * (TSTEPS * HDIM)
                                           + (size_t)(t - 1) * HDIM + c0);
                    o1[0] = make_float4(v[0], v[1], v[2], v[3]);
                    o1[1] = make_float4(v[4], v[5], v[6], v[7]);
                }
            } else {
                const int cm = 16 * (b - 64) + 8 * half;
                float v[8];
#pragma unroll
                for (int j = 0; j < 8; ++j) v[j] = acc[j] + biasA[j];
                float4* o = (float4*)(mh + (size_t)row * TH3 + cm);
                o[0] = make_float4(v[0], v[1], v[2], v[3]);
                o[1] = make_float4(v[4], v[5], v[6], v[7]);
            }
        }
        if (t == TSTEPS) break;
        grid.sync();

        // ===== phase B: mx = outb @ W_k, fused gates -> h =====
        {
            const float* A = outb + (size_t)row * HDIM;
            float az0 = 0, ar0 = 0, ah0 = 0, az1 = 0, ar1 = 0, ah1 = 0;
            float4 an = *(const float4*)(A);
            for (int k4 = 0; k4 < 256; ++k4) {
                const float4 ac = an;
                an = *(const float4*)(A + 4 * (k4 + 1));
#pragma unroll
                for (int kk = 0; kk < 4; ++kk) {
                    const int k = 4 * k4 + kk;
                    const float av = (&ac.x)[kk];
                    const float4 w0 = *(const float4*)(WB + k * 16 + 8 * half);
                    const float4 w1 = *(const float4*)(WB + k * 16 + 8 * half + 4);
                    az0 = fmaf(av, w0.x, az0);
                    ar0 = fmaf(av, w0.y, ar0);
                    ah0 = fmaf(av, w0.z, ah0);
                    az1 = fmaf(av, w1.x, az1);
                    ar1 = fmaf(av, w1.y, ar1);
                    ah1 = fmaf(av, w1.z, ah1);
                }
            }
            const float* mhp = mh + (size_t)row * TH3;
            {
                const int j = 4 * b + 2 * half;
                const float z = sigmoidf_(az0 + bz[0] + mhp[j]);
                const float r = sigmoidf_(ar0 + br[0] + mhp[HDIM + j]);
                const float cand = tanhf(ah0 + bh[0] + r * mhp[2 * HDIM + j]);
                const size_t hi = (size_t)row * HDIM + j;
                const float ho = h[hi];
                h[hi] = z * ho + (1.0f - z) * cand;
            }
            {
                const int j = 4 * b + 2 * half + 1;
                const float z = sigmoidf_(az1 + bz[1] + mhp[j]);
                const float r = sigmoidf_(ar1 + br[1] + mhp[HDIM + j]);
                const float cand = tanhf(ah1 + bh[1] + r * mhp[2 * HDIM + j]);
                const size_t hi = (size_t)row * HDIM + j;
                const float ho = h[hi];
                h[hi] = z * ho + (1.0f - z) * cand;
            }
        }
        grid.sync();
    }
}

// ===========================================================================
// Fallback path (round-2 kernels) — used only if cooperative launch fails.
// ===========================================================================
__global__ __launch_bounds__(128) void gemmA(
    const float* __restrict__ A,
    const float* __restrict__ W0, const float* __restrict__ b0, int act0,
    float* __restrict__ C0, float* __restrict__ C2,
    const float* __restrict__ W1, const float* __restrict__ b1,
    float* __restrict__ C1)
{
    __shared__ __align__(16) float As[32][36];
    __shared__ __align__(16) float Ws[32][68];
    const int tid = threadIdx.x;
    const int bx = blockIdx.x, by = blockIdx.y;
    const int r0 = by * 32;
    const bool reg0 = (bx < 16);
    const int c0 = reg0 ? bx * 64 : (bx - 16) * 64;
    const float* __restrict__ W = reg0 ? W0 : W1;
    const int ldw = reg0 ? 1024 : 3072;
    const int arow = tid >> 2;
    const int ak   = (tid & 3) << 2;
    const int wrow = tid >> 4;
    const int wcol = (tid & 15) << 2;
    const int ty = tid >> 4;
    const int tx = tid & 15;
    float acc[4][4] = {};
    const float* Ap = A + (size_t)(r0 + arow) * 1024 + ak;
    const float* Wp = W + (size_t)wrow * ldw + c0 + wcol;
    for (int k0 = 0; k0 < 1024; k0 += 32) {
        const float4 a0 = *(const float4*)(Ap + k0);
        const float4 a1 = *(const float4*)(Ap + k0 + 16);
        const float4 w0 = *(const float4*)(Wp + (size_t)k0 * ldw);
        const float4 w1 = *(const float4*)(Wp + (size_t)(k0 + 8) * ldw);
        const float4 w2 = *(const float4*)(Wp + (size_t)(k0 + 16) * ldw);
        const float4 w3 = *(const float4*)(Wp + (size_t)(k0 + 24) * ldw);
        __syncthreads();
        As[ak + 0][arow] = a0.x; As[ak + 1][arow] = a0.y;
        As[ak + 2][arow] = a0.z; As[ak + 3][arow] = a0.w;
        As[ak + 16][arow] = a1.x; As[ak + 17][arow] = a1.y;
        As[ak + 18][arow] = a1.z; As[ak + 19][arow] = a1.w;
        *(float4*)&Ws[wrow][wcol]      = w0;
        *(float4*)&Ws[wrow + 8][wcol]  = w1;
        *(float4*)&Ws[wrow + 16][wcol] = w2;
        *(float4*)&Ws[wrow + 24][wcol] = w3;
        __syncthreads();
#pragma unroll
        for (int kk = 0; kk < 32; ++kk) {
            const float4 a4 = *(const float4*)&As[kk][ty << 2];
            const float4 w4 = *(const float4*)&Ws[kk][tx << 2];
            const float a[4] = {a4.x, a4.y, a4.z, a4.w};
            const float w[4] = {w4.x, w4.y, w4.z, w4.w};
#pragma unroll
            for (int i = 0; i < 4; ++i)
#pragma unroll
                for (int j = 0; j < 4; ++j)
                    acc[i][j] = fmaf(a[i], w[j], acc[i][j]);
        }
    }
    const float* bias = reg0 ? b0 : b1;
    const float4 bv = *(const float4*)(bias + c0 + (tx << 2));
    const float bb[4] = {bv.x, bv.y, bv.z, bv.w};
#pragma unroll
    for (int i = 0; i < 4; ++i) {
        const int row = r0 + (ty << 2) + i;
        float v[4];
#pragma unroll
        for (int j = 0; j < 4; ++j) {
            float t = acc[i][j] + bb[j];
            if (reg0) { t = (act0 == 1) ? fmaxf(t, 0.0f) : tanhf(t); }
            v[j] = t;
        }
        const float4 o = make_float4(v[0], v[1], v[2], v[3]);
        if (reg0) {
            *(float4*)(C0 + (size_t)row * 1024 + c0 + (tx << 2)) = o;
            if (C2)
                *(float4*)(C2 + (size_t)row * (TSTEPS * HDIM) + c0 + (tx << 2)) = o;
        } else {
            *(float4*)(C1 + (size_t)row * TH3 + c0 + (tx << 2)) = o;
        }
    }
}

__global__ __launch_bounds__(128) void gemmB(
    const float* __restrict__ A,
    const float* __restrict__ Wk,
    const float* __restrict__ bg,
    const float* __restrict__ mh,
    float* __restrict__ h)
{
    __shared__ __align__(16) float As[32][36];
    __shared__ __align__(16) float Ws[3][32][20];
    const int tid = threadIdx.x;
    const int j0 = blockIdx.x * 16;
    const int r0 = blockIdx.y * 32;
    const int arow = tid >> 2;
    const int ak   = (tid & 3) << 2;
    const int wr   = tid >> 2;
    const int wc   = (tid & 3) << 2;
    const int ty = tid >> 4;
    const int tx = tid & 15;
    float acc[3][4] = {};
    const float* Ap = A + (size_t)(r0 + arow) * 1024 + ak;
    const float* Wp = Wk + (size_t)wr * TH3 + j0 + wc;
    for (int k0 = 0; k0 < 1024; k0 += 32) {
        const float4 a0 = *(const float4*)(Ap + k0);
        const float4 a1 = *(const float4*)(Ap + k0 + 16);
        float4 wv[3];
#pragma unroll
        for (int c = 0; c < 3; ++c)
            wv[c] = *(const float4*)(Wp + (size_t)k0 * TH3 + c * 1024);
        __syncthreads();
        As[ak + 0][arow] = a0.x; As[ak + 1][arow] = a0.y;
        As[ak + 2][arow] = a0.z; As[ak + 3][arow] = a0.w;
        As[ak + 16][arow] = a1.x; As[ak + 17][arow] = a1.y;
        As[ak + 18][arow] = a1.z; As[ak + 19][arow] = a1.w;
#pragma unroll
        for (int c = 0; c < 3; ++c)
            *(float4*)&Ws[c][wr][wc] = wv[c];
        __syncthreads();
#pragma unroll
        for (int kk = 0; kk < 32; ++kk) {
            const float4 a4 = *(const float4*)&As[kk][ty << 2];
            const float a[4] = {a4.x, a4.y, a4.z, a4.w};
            const float wz = Ws[0][kk][tx];
            const float wr_ = Ws[1][kk][tx];
            const float wh = Ws[2][kk][tx];
#pragma unroll
            for (int i = 0; i < 4; ++i) {
                acc[0][i] = fmaf(a[i], wz, acc[0][i]);
                acc[1][i] = fmaf(a[i], wr_, acc[1][i]);
                acc[2][i] = fmaf(a[i], wh, acc[2][i]);
            }
        }
    }
    const int j = j0 + tx;
    const float bz = bg[j];
    const float br = bg[HDIM + j];
    const float bh = bg[2 * HDIM + j];
#pragma unroll
    for (int i = 0; i < 4; ++i) {
        const int row = r0 + (ty << 2) + i;
        const float* mhp = mh + (size_t)row * TH3;
        const float z  = sigmoidf_(acc[0][i] + bz + mhp[j]);
        const float rg = sigmoidf_(acc[1][i] + br + mhp[HDIM + j]);
        const float cand = tanhf(acc[2][i] + bh + rg * mhp[2 * HDIM + j]);
        const size_t hi = (size_t)row * HDIM + j;
        const float ho = h[hi];
        h[hi] = z * ho + (1.0f - z) * cand;
    }
}

extern "C" void kernel_launch(void* const* d_in, const int* in_sizes, int n_in,
                              void* d_out, int out_size, void* d_ws, size_t ws_size,
                              hipStream_t stream) {
    const float* x     = (const float*)d_in[0];
    const float* W_fs  = (const float*)d_in[1];
    const float* b_fs  = (const float*)d_in[2];
    const float* W_out = (const float*)d_in[3];
    const float* b_out = (const float*)d_in[4];
    const float* W_k   = (const float*)d_in[5];
    const float* W_r   = (const float*)d_in[6];
    const float* b_gru = (const float*)d_in[7];
    float* out = (float*)d_out;            // [B, T, H]

    float* h    = (float*)d_ws;            // [256,1024]
    float* outb = h    + BDIM * HDIM;      // [256,1024]
    float* mh   = outb + BDIM * HDIM;      // [256,3072]

    void* args[] = {
        (void*)&x, (void*)&W_fs, (void*)&b_fs, (void*)&W_out, (void*)&b_out,
        (void*)&W_k, (void*)&W_r, (void*)&b_gru, (void*)&out,
        (void*)&h, (void*)&outb, (void*)&mh
    };
    hipError_t err = hipLaunchCooperativeKernel(
        (const void*)decoder_persistent, dim3(256), dim3(512),
        args, 128 * 1024, stream);

    if (err != hipSuccess) {
        // fallback: round-2 multi-launch path
        const dim3 blk(128);
        const dim3 gridInit(16, 8);
        const dim3 gridA(64, 8);
        const dim3 gridB(64, 8);
        gemmA<<<gridInit, blk, 0, stream>>>(x, W_fs, b_fs, 2, h, nullptr,
                                            nullptr, nullptr, nullptr);
        for (int t = 0; t < TSTEPS; ++t) {
            float* c2 = (t >= 1) ? (out + (size_t)(t - 1) * HDIM) : nullptr;
            gemmA<<<gridA, blk, 0, stream>>>(h, W_out, b_out, 1, outb, c2,
                                             W_r, b_gru + TH3, mh);
            gemmB<<<gridB, blk, 0, stream>>>(outb, W_k, b_gru, mh, h);
        }
        gemmA<<<gridInit, blk, 0, stream>>>(h, W_out, b_out, 1, outb,
                                            out + (size_t)(TSTEPS - 1) * HDIM,
                                            nullptr, nullptr, nullptr);
    }
}

// Round 4
// 11831.466 us; speedup vs baseline: 1.2174x; 1.2174x over previous
//
#include <hip/hip_runtime.h>
#include <hip/hip_cooperative_groups.h>
#include <math.h>

namespace cg = cooperative_groups;

#define HDIM 1024
#define BDIM 256
#define TSTEPS 64
#define TH3 3072
#define RS 260            // As row stride in words per k-slice (aligned, low-conflict)

__device__ __forceinline__ float sigmoidf_(float x) {
    return 1.0f / (1.0f + __expf(-x));
}

// Stage helpers: A chunk [256 rows][k0..k0+31] -> As[k][row] (transposed).
// Global loads: lane-contiguous along k within a row (coalesced 128B/row).
__device__ __forceinline__ void stage_issue(const float* __restrict__ src,
                                            int k0, int tid, float4* tmp) {
#pragma unroll
    for (int q = 0; q < 8; ++q) {
        const int f = tid + 256 * q;
        const int row = f >> 3, kq = f & 7;
        tmp[q] = *(const float4*)(src + (size_t)row * HDIM + k0 + 4 * kq);
    }
}
__device__ __forceinline__ void stage_write(float* __restrict__ As,
                                            int tid, const float4* tmp) {
#pragma unroll
    for (int q = 0; q < 8; ++q) {
        const int f = tid + 256 * q;
        const int row = f >> 3, kq = f & 7;
        As[(4 * kq + 0) * RS + row] = tmp[q].x;
        As[(4 * kq + 1) * RS + row] = tmp[q].y;
        As[(4 * kq + 2) * RS + row] = tmp[q].z;
        As[(4 * kq + 3) * RS + row] = tmp[q].w;
    }
}

// ===========================================================================
// Persistent cooperative kernel: 256 blocks x 256 threads, 1 block/CU.
// LDS (145 KB): WA[1024][16] = this block's 16 cols of [W_out|W_r] (or W_fs
// during phase 0); WBz/WBr/WBh[1024][4] = W_k cols 4b..4b+3 per gate chunk;
// As[32][RS] = staged k-chunk of the activation matrix, transposed.
// Thread (rg=tid>>2, cq=tid&3) owns rows 4rg..4rg+3:
//   phase A: 4x4 tile, cols 16b+4cq..+3 of [out|mh]; per k: 1 A-b128 + 1
//            W-b128 -> 16 FMA.
//   phase B: 4 rows x (z,r,h) at j=4b+cq; fused GRU gates write h in place.
// ===========================================================================
__global__ __launch_bounds__(256, 1) void decoder_persistent(
    const float* __restrict__ x,
    const float* __restrict__ W_fs, const float* __restrict__ b_fs,
    const float* __restrict__ W_out, const float* __restrict__ b_out,
    const float* __restrict__ W_k,  const float* __restrict__ W_r,
    const float* __restrict__ b_gru,
    float* __restrict__ dout,
    float* __restrict__ h, float* __restrict__ outb, float* __restrict__ mh)
{
    extern __shared__ float lds[];
    float* WA  = lds;            // [1024][16]
    float* WBz = lds + 16384;    // [1024][4]
    float* WBr = lds + 20480;    // [1024][4]
    float* WBh = lds + 24576;    // [1024][4]
    float* As  = lds + 28672;    // [32][RS]

    cg::grid_group grid = cg::this_grid();
    const int b   = blockIdx.x;
    const int tid = threadIdx.x;
    const int rg  = tid >> 2;
    const int cq  = tid & 3;
    const int r0  = rg << 2;

    // ---------------- phase 0: h0 = tanh(x @ W_fs + b_fs) (blocks 0..63) ---
    if (b < 64) {
        for (int f = tid; f < 4096; f += 256) {
            const int k = f >> 2, cd = f & 3;
            *(float4*)&WA[k * 16 + 4 * cd] =
                *(const float4*)(W_fs + (size_t)k * HDIM + 16 * b + 4 * cd);
        }
        __syncthreads();
        const float4 bias = *(const float4*)(b_fs + 16 * b + 4 * cq);
        float acc[4][4] = {};
        float4 tmp[8];
        stage_issue(x, 0, tid, tmp);
        for (int k0 = 0; k0 < HDIM; k0 += 32) {
            __syncthreads();
            stage_write(As, tid, tmp);
            __syncthreads();
            if (k0 + 32 < HDIM) stage_issue(x, k0 + 32, tid, tmp);
#pragma unroll
            for (int k = 0; k < 32; ++k) {
                const float4 av = *(const float4*)&As[k * RS + r0];
                const float4 wv = *(const float4*)&WA[(k0 + k) * 16 + 4 * cq];
                const float a[4] = {av.x, av.y, av.z, av.w};
                const float w[4] = {wv.x, wv.y, wv.z, wv.w};
#pragma unroll
                for (int i = 0; i < 4; ++i)
#pragma unroll
                    for (int j = 0; j < 4; ++j)
                        acc[i][j] = fmaf(a[i], w[j], acc[i][j]);
            }
        }
        const float bb[4] = {bias.x, bias.y, bias.z, bias.w};
#pragma unroll
        for (int i = 0; i < 4; ++i) {
            float4 v;
            v.x = tanhf(acc[i][0] + bb[0]);
            v.y = tanhf(acc[i][1] + bb[1]);
            v.z = tanhf(acc[i][2] + bb[2]);
            v.w = tanhf(acc[i][3] + bb[3]);
            *(float4*)(h + (size_t)(r0 + i) * HDIM + 16 * b + 4 * cq) = v;
        }
        __syncthreads();   // WA about to be refilled
    }

    // ---------------- one-time weight fills ----------------
    {
        const float* Wsrc = (b < 64) ? W_out : W_r;
        const int ldw     = (b < 64) ? HDIM : TH3;
        const int col0    = (b < 64) ? 16 * b : 16 * (b - 64);
        for (int f = tid; f < 4096; f += 256) {
            const int k = f >> 2, cd = f & 3;
            *(float4*)&WA[k * 16 + 4 * cd] =
                *(const float4*)(Wsrc + (size_t)k * ldw + col0 + 4 * cd);
        }
        for (int f = tid; f < 4096; f += 256) {
            const int k = f >> 2, jq = f & 3;
            const size_t base = (size_t)k * TH3 + 4 * b + jq;
            WBz[k * 4 + jq] = W_k[base];
            WBr[k * 4 + jq] = W_k[base + HDIM];
            WBh[k * 4 + jq] = W_k[base + 2 * HDIM];
        }
    }

    // phase-A bias (per-thread 4 cols)
    float4 biasA = (b < 64)
        ? *(const float4*)(b_out + 16 * b + 4 * cq)
        : *(const float4*)(b_gru + TH3 + 16 * (b - 64) + 4 * cq);
    const float bA[4] = {biasA.x, biasA.y, biasA.z, biasA.w};
    // phase-B biases (j = 4b + cq)
    const int jB = 4 * b + cq;
    const float bz = b_gru[jB];
    const float br = b_gru[HDIM + jB];
    const float bh = b_gru[2 * HDIM + jB];

    grid.sync();   // h0 complete, weights resident

    // ---------------- recurrence ----------------
    for (int t = 0; t <= TSTEPS; ++t) {
        // ===== phase A: [out | mh] = h @ [W_out | W_r] =====
        if (t < TSTEPS || b < 64) {
            float acc[4][4] = {};
            float4 tmp[8];
            stage_issue(h, 0, tid, tmp);
            for (int k0 = 0; k0 < HDIM; k0 += 32) {
                __syncthreads();
                stage_write(As, tid, tmp);
                __syncthreads();
                if (k0 + 32 < HDIM) stage_issue(h, k0 + 32, tid, tmp);
#pragma unroll
                for (int k = 0; k < 32; ++k) {
                    const float4 av = *(const float4*)&As[k * RS + r0];
                    const float4 wv = *(const float4*)&WA[(k0 + k) * 16 + 4 * cq];
                    const float a[4] = {av.x, av.y, av.z, av.w};
                    const float w[4] = {wv.x, wv.y, wv.z, wv.w};
#pragma unroll
                    for (int i = 0; i < 4; ++i)
#pragma unroll
                        for (int j = 0; j < 4; ++j)
                            acc[i][j] = fmaf(a[i], w[j], acc[i][j]);
                }
            }
            if (b < 64) {
                const int c0 = 16 * b + 4 * cq;
#pragma unroll
                for (int i = 0; i < 4; ++i) {
                    float4 v;
                    v.x = fmaxf(acc[i][0] + bA[0], 0.0f);
                    v.y = fmaxf(acc[i][1] + bA[1], 0.0f);
                    v.z = fmaxf(acc[i][2] + bA[2], 0.0f);
                    v.w = fmaxf(acc[i][3] + bA[3], 0.0f);
                    if (t < TSTEPS)
                        *(float4*)(outb + (size_t)(r0 + i) * HDIM + c0) = v;
                    if (t >= 1)
                        *(float4*)(dout + (size_t)(r0 + i) * (TSTEPS * HDIM)
                                   + (size_t)(t - 1) * HDIM + c0) = v;
                }
            } else {
                const int c0 = 16 * (b - 64) + 4 * cq;
#pragma unroll
                for (int i = 0; i < 4; ++i) {
                    float4 v;
                    v.x = acc[i][0] + bA[0];
                    v.y = acc[i][1] + bA[1];
                    v.z = acc[i][2] + bA[2];
                    v.w = acc[i][3] + bA[3];
                    *(float4*)(mh + (size_t)(r0 + i) * TH3 + c0) = v;
                }
            }
        }
        if (t == TSTEPS) break;
        grid.sync();

        // ===== phase B: mx = out @ W_k, fused GRU gates -> h =====
        {
            float az[4] = {}, ar[4] = {}, ah[4] = {};
            float4 tmp[8];
            stage_issue(outb, 0, tid, tmp);
            for (int k0 = 0; k0 < HDIM; k0 += 32) {
                __syncthreads();
                stage_write(As, tid, tmp);
                __syncthreads();
                if (k0 + 32 < HDIM) stage_issue(outb, k0 + 32, tid, tmp);
#pragma unroll
                for (int k = 0; k < 32; ++k) {
                    const float4 av = *(const float4*)&As[k * RS + r0];
                    const int kg = (k0 + k) * 4 + cq;
                    const float wz = WBz[kg];
                    const float wr = WBr[kg];
                    const float wh = WBh[kg];
                    const float a[4] = {av.x, av.y, av.z, av.w};
#pragma unroll
                    for (int i = 0; i < 4; ++i) {
                        az[i] = fmaf(a[i], wz, az[i]);
                        ar[i] = fmaf(a[i], wr, ar[i]);
                        ah[i] = fmaf(a[i], wh, ah[i]);
                    }
                }
            }
#pragma unroll
            for (int i = 0; i < 4; ++i) {
                const int row = r0 + i;
                const float* mhp = mh + (size_t)row * TH3;
                const float z    = sigmoidf_(az[i] + bz + mhp[jB]);
                const float rg_  = sigmoidf_(ar[i] + br + mhp[HDIM + jB]);
                const float cand = tanhf(ah[i] + bh + rg_ * mhp[2 * HDIM + jB]);
                const size_t hi = (size_t)row * HDIM + jB;
                const float ho = h[hi];
                h[hi] = z * ho + (1.0f - z) * cand;
            }
        }
        grid.sync();
    }
}

// ===========================================================================
// Fallback path (round-2 kernels) — used only if cooperative launch fails.
// ===========================================================================
__global__ __launch_bounds__(128) void gemmA(
    const float* __restrict__ A,
    const float* __restrict__ W0, const float* __restrict__ b0, int act0,
    float* __restrict__ C0, float* __restrict__ C2,
    const float* __restrict__ W1, const float* __restrict__ b1,
    float* __restrict__ C1)
{
    __shared__ __align__(16) float Ass[32][36];
    __shared__ __align__(16) float Ws[32][68];
    const int tid = threadIdx.x;
    const int bx = blockIdx.x, by = blockIdx.y;
    const int r0 = by * 32;
    const bool reg0 = (bx < 16);
    const int c0 = reg0 ? bx * 64 : (bx - 16) * 64;
    const float* __restrict__ W = reg0 ? W0 : W1;
    const int ldw = reg0 ? 1024 : 3072;
    const int arow = tid >> 2;
    const int ak   = (tid & 3) << 2;
    const int wrow = tid >> 4;
    const int wcol = (tid & 15) << 2;
    const int ty = tid >> 4;
    const int tx = tid & 15;
    float acc[4][4] = {};
    const float* Ap = A + (size_t)(r0 + arow) * 1024 + ak;
    const float* Wp = W + (size_t)wrow * ldw + c0 + wcol;
    for (int k0 = 0; k0 < 1024; k0 += 32) {
        const float4 a0 = *(const float4*)(Ap + k0);
        const float4 a1 = *(const float4*)(Ap + k0 + 16);
        const float4 w0 = *(const float4*)(Wp + (size_t)k0 * ldw);
        const float4 w1 = *(const float4*)(Wp + (size_t)(k0 + 8) * ldw);
        const float4 w2 = *(const float4*)(Wp + (size_t)(k0 + 16) * ldw);
        const float4 w3 = *(const float4*)(Wp + (size_t)(k0 + 24) * ldw);
        __syncthreads();
        Ass[ak + 0][arow] = a0.x; Ass[ak + 1][arow] = a0.y;
        Ass[ak + 2][arow] = a0.z; Ass[ak + 3][arow] = a0.w;
        Ass[ak + 16][arow] = a1.x; Ass[ak + 17][arow] = a1.y;
        Ass[ak + 18][arow] = a1.z; Ass[ak + 19][arow] = a1.w;
        *(float4*)&Ws[wrow][wcol]      = w0;
        *(float4*)&Ws[wrow + 8][wcol]  = w1;
        *(float4*)&Ws[wrow + 16][wcol] = w2;
        *(float4*)&Ws[wrow + 24][wcol] = w3;
        __syncthreads();
#pragma unroll
        for (int kk = 0; kk < 32; ++kk) {
            const float4 a4 = *(const float4*)&Ass[kk][ty << 2];
            const float4 w4 = *(const float4*)&Ws[kk][tx << 2];
            const float a[4] = {a4.x, a4.y, a4.z, a4.w};
            const float w[4] = {w4.x, w4.y, w4.z, w4.w};
#pragma unroll
            for (int i = 0; i < 4; ++i)
#pragma unroll
                for (int j = 0; j < 4; ++j)
                    acc[i][j] = fmaf(a[i], w[j], acc[i][j]);
        }
    }
    const float* bias = reg0 ? b0 : b1;
    const float4 bv = *(const float4*)(bias + c0 + (tx << 2));
    const float bb[4] = {bv.x, bv.y, bv.z, bv.w};
#pragma unroll
    for (int i = 0; i < 4; ++i) {
        const int row = r0 + (ty << 2) + i;
        float v[4];
#pragma unroll
        for (int j = 0; j < 4; ++j) {
            float tv = acc[i][j] + bb[j];
            if (reg0) { tv = (act0 == 1) ? fmaxf(tv, 0.0f) : tanhf(tv); }
            v[j] = tv;
        }
        const float4 o = make_float4(v[0], v[1], v[2], v[3]);
        if (reg0) {
            *(float4*)(C0 + (size_t)row * 1024 + c0 + (tx << 2)) = o;
            if (C2)
                *(float4*)(C2 + (size_t)row * (TSTEPS * HDIM) + c0 + (tx << 2)) = o;
        } else {
            *(float4*)(C1 + (size_t)row * TH3 + c0 + (tx << 2)) = o;
        }
    }
}

__global__ __launch_bounds__(128) void gemmB(
    const float* __restrict__ A,
    const float* __restrict__ Wk,
    const float* __restrict__ bg,
    const float* __restrict__ mh,
    float* __restrict__ h)
{
    __shared__ __align__(16) float Ass[32][36];
    __shared__ __align__(16) float Ws[3][32][20];
    const int tid = threadIdx.x;
    const int j0 = blockIdx.x * 16;
    const int r0 = blockIdx.y * 32;
    const int arow = tid >> 2;
    const int ak   = (tid & 3) << 2;
    const int wr   = tid >> 2;
    const int wc   = (tid & 3) << 2;
    const int ty = tid >> 4;
    const int tx = tid & 15;
    float acc[3][4] = {};
    const float* Ap = A + (size_t)(r0 + arow) * 1024 + ak;
    const float* Wp = Wk + (size_t)wr * TH3 + j0 + wc;
    for (int k0 = 0; k0 < 1024; k0 += 32) {
        const float4 a0 = *(const float4*)(Ap + k0);
        const float4 a1 = *(const float4*)(Ap + k0 + 16);
        float4 wv[3];
#pragma unroll
        for (int c = 0; c < 3; ++c)
            wv[c] = *(const float4*)(Wp + (size_t)k0 * TH3 + c * 1024);
        __syncthreads();
        Ass[ak + 0][arow] = a0.x; Ass[ak + 1][arow] = a0.y;
        Ass[ak + 2][arow] = a0.z; Ass[ak + 3][arow] = a0.w;
        Ass[ak + 16][arow] = a1.x; Ass[ak + 17][arow] = a1.y;
        Ass[ak + 18][arow] = a1.z; Ass[ak + 19][arow] = a1.w;
#pragma unroll
        for (int c = 0; c < 3; ++c)
            *(float4*)&Ws[c][wr][wc] = wv[c];
        __syncthreads();
#pragma unroll
        for (int kk = 0; kk < 32; ++kk) {
            const float4 a4 = *(const float4*)&Ass[kk][ty << 2];
            const float a[4] = {a4.x, a4.y, a4.z, a4.w};
            const float wz = Ws[0][kk][tx];
            const float wr_ = Ws[1][kk][tx];
            const float wh = Ws[2][kk][tx];
#pragma unroll
            for (int i = 0; i < 4; ++i) {
                acc[0][i] = fmaf(a[i], wz, acc[0][i]);
                acc[1][i] = fmaf(a[i], wr_, acc[1][i]);
                acc[2][i] = fmaf(a[i], wh, acc[2][i]);
            }
        }
    }
    const int j = j0 + tx;
    const float bz = bg[j];
    const float br = bg[HDIM + j];
    const float bh = bg[2 * HDIM + j];
#pragma unroll
    for (int i = 0; i < 4; ++i) {
        const int row = r0 + (ty << 2) + i;
        const float* mhp = mh + (size_t)row * TH3;
        const float z  = sigmoidf_(acc[0][i] + bz + mhp[j]);
        const float rg = sigmoidf_(acc[1][i] + br + mhp[HDIM + j]);
        const float cand = tanhf(acc[2][i] + bh + rg * mhp[2 * HDIM + j]);
        const size_t hi = (size_t)row * HDIM + j;
        const float ho = h[hi];
        h[hi] = z * ho + (1.0f - z) * cand;
    }
}

extern "C" void kernel_launch(void* const* d_in, const int* in_sizes, int n_in,
                              void* d_out, int out_size, void* d_ws, size_t ws_size,
                              hipStream_t stream) {
    const float* x     = (const float*)d_in[0];
    const float* W_fs  = (const float*)d_in[1];
    const float* b_fs  = (const float*)d_in[2];
    const float* W_out = (const float*)d_in[3];
    const float* b_out = (const float*)d_in[4];
    const float* W_k   = (const float*)d_in[5];
    const float* W_r   = (const float*)d_in[6];
    const float* b_gru = (const float*)d_in[7];
    float* out = (float*)d_out;            // [B, T, H]

    float* h    = (float*)d_ws;            // [256,1024]
    float* outb = h    + BDIM * HDIM;      // [256,1024]
    float* mh   = outb + BDIM * HDIM;      // [256,3072]

    void* args[] = {
        (void*)&x, (void*)&W_fs, (void*)&b_fs, (void*)&W_out, (void*)&b_out,
        (void*)&W_k, (void*)&W_r, (void*)&b_gru, (void*)&out,
        (void*)&h, (void*)&outb, (void*)&mh
    };
    // dynamic LDS: (16384 + 3*4096 + 32*RS) floats = 147,968 B
    const size_t lds_bytes = (16384 + 3 * 4096 + 32 * RS) * sizeof(float);
    hipError_t err = hipLaunchCooperativeKernel(
        (const void*)decoder_persistent, dim3(256), dim3(256),
        args, lds_bytes, stream);

    if (err != hipSuccess) {
        // fallback: round-2 multi-launch path
        const dim3 blk(128);
        const dim3 gridInit(16, 8);
        const dim3 gridA(64, 8);
        const dim3 gridB(64, 8);
        gemmA<<<gridInit, blk, 0, stream>>>(x, W_fs, b_fs, 2, h, nullptr,
                                            nullptr, nullptr, nullptr);
        for (int t = 0; t < TSTEPS; ++t) {
            float* c2 = (t >= 1) ? (out + (size_t)(t - 1) * HDIM) : nullptr;
            gemmA<<<gridA, blk, 0, stream>>>(h, W_out, b_out, 1, outb, c2,
                                             W_r, b_gru + TH3, mh);
            gemmB<<<gridB, blk, 0, stream>>>(outb, W_k, b_gru, mh, h);
        }
        gemmA<<<gridInit, blk, 0, stream>>>(h, W_out, b_out, 1, outb,
                                            out + (size_t)(TSTEPS - 1) * HDIM,
                                            nullptr, nullptr, nullptr);
    }
}

// Round 5
// 6309.505 us; speedup vs baseline: 2.2829x; 1.8752x over previous
//
#include <hip/hip_runtime.h>
#include <hip/hip_cooperative_groups.h>
#include <math.h>

namespace cg = cooperative_groups;

#define HDIM 1024
#define BROWS 256
#define TSTEPS 64
#define TH3 3072
#define RSCALE 1024.0f
#define RINV   0.0009765625f   // 2^-10

typedef _Float16 half8 __attribute__((ext_vector_type(8)));
typedef float float4v __attribute__((ext_vector_type(4)));

__device__ __forceinline__ float sigmoidf_(float x) {
    return 1.0f / (1.0f + __expf(-x));
}

// halfword index of element (m,k) in a [256][1024] plane stored in MFMA
// A-fragment order: [mtile][ktile][lane][slot], lane=(m&15)+16*((k&31)>>3),
// slot=k&7. A wave's (mtile,ktile) fragment is 1KB contiguous.
__device__ __forceinline__ int frag_idx(int m, int k) {
    return (((m >> 4) * 32 + (k >> 5)) * 64 + ((m & 15) + (((k & 31) >> 3) << 4))) * 8 + (k & 7);
}

__device__ __forceinline__ void split16(float v, _Float16* hp, _Float16* lp) {
    const _Float16 h = (_Float16)v;
    *hp = h;
    *lp = (_Float16)((v - (float)h) * RSCALE);
}

// ===========================================================================
// Persistent cooperative kernel: 256 blocks x 512 threads (8 waves, 2/SIMD).
// LDS 128KB: WAh/WAl = 16 cols of [W_out|W_r] as B-fragments (split fp16),
//            WBh/WBl = 12 interleaved gate cols of W_k (n=jj*3+chunk, 4 jj).
// Activations in global as split-fp16 A-fragment planes (hH/hL, oH/oL).
// Per step: phase A: [out|mh] = h @ [W_out|W_r] (MFMA, 3-pass split)
//           phase B: mx = out @ W_k + fused GRU gates -> h planes in place.
// ===========================================================================
__global__ __launch_bounds__(512, 2) void decoder_mfma(
    const float* __restrict__ x,
    const float* __restrict__ W_fs, const float* __restrict__ b_fs,
    const float* __restrict__ W_out, const float* __restrict__ b_out,
    const float* __restrict__ W_k,  const float* __restrict__ W_r,
    const float* __restrict__ b_gru,
    float* __restrict__ dout,
    _Float16* __restrict__ hH, _Float16* __restrict__ hL,
    _Float16* __restrict__ oH, _Float16* __restrict__ oL,
    float* __restrict__ mh)
{
    extern __shared__ _Float16 ldsh[];
    _Float16* WAh = ldsh;              // 16384 halves = 32KB
    _Float16* WAl = ldsh + 16384;
    _Float16* WBh = ldsh + 32768;
    _Float16* WBl = ldsh + 49152;

    cg::grid_group grid = cg::this_grid();
    const int b    = blockIdx.x;
    const int tid  = threadIdx.x;
    const int wv   = tid >> 6;         // wave 0..7
    const int lane = tid & 63;
    const int nn   = lane & 15;        // fragment n / C col
    const int kq   = lane >> 4;        // fragment k-quad / C row-quad

    // ---------- one-time: pack weight panels into LDS fragment order -------
    {
        const float* srcA; int ldwA, coffA;
        if (b < 64) { srcA = W_out; ldwA = HDIM; coffA = 16 * b; }
        else        { srcA = W_r;   ldwA = TH3;  coffA = 16 * b - 1024; }
        for (int idx = tid; idx < 16384; idx += 512) {
            const int k = idx >> 4, n = idx & 15;
            const float w = srcA[(size_t)k * ldwA + coffA + n];
            const int hw = ((k >> 5) * 64 + n + (((k & 31) >> 3) << 4)) * 8 + (k & 7);
            split16(w, &WAh[hw], &WAl[hw]);
        }
        for (int idx = tid; idx < 16384; idx += 512) {
            const int k = idx >> 4, n = idx & 15;
            float w = 0.0f;
            if (n < 12) {
                const int jj = n / 3, ch = n - 3 * jj;
                w = W_k[(size_t)k * TH3 + ch * 1024 + 4 * b + jj];
            }
            const int hw = ((k >> 5) * 64 + n + (((k & 31) >> 3) << 4)) * 8 + (k & 7);
            split16(w, &WBh[hw], &WBl[hw]);
        }
    }

    // ---------- biases ----------
    const int cA = 16 * b + nn;                      // phase-A concat col
    const float bA = (b < 64) ? b_out[cA] : b_gru[TH3 + cA - 1024];
    float bB = 0.0f;                                 // phase-B col bias (b_gru[0])
    if (nn < 12) {
        const int jj = nn / 3, ch = nn - 3 * jj;
        bB = b_gru[ch * 1024 + 4 * b + jj];
    }

    // ---------- phase 0: h0 = tanh(x @ W_fs + b_fs), 4 cols/block ----------
    {
        const int row = tid & 255;
        const int c = 4 * b + ((tid >> 8) << 1);     // 2 cols per thread
        float a0 = 0.0f, a1 = 0.0f;
        const float* xr = x + (size_t)row * HDIM;
        for (int k = 0; k < HDIM; k += 4) {
            const float4 xv = *(const float4*)(xr + k);
#pragma unroll
            for (int kk = 0; kk < 4; ++kk) {
                const float2 wv2 = *(const float2*)(W_fs + (size_t)(k + kk) * HDIM + c);
                const float av = (&xv.x)[kk];
                a0 = fmaf(av, wv2.x, a0);
                a1 = fmaf(av, wv2.y, a1);
            }
        }
        const float h0 = tanhf(a0 + b_fs[c]);
        const float h1 = tanhf(a1 + b_fs[c + 1]);
        split16(h0, &hH[frag_idx(row, c)],     &hL[frag_idx(row, c)]);
        split16(h1, &hH[frag_idx(row, c + 1)], &hL[frag_idx(row, c + 1)]);
    }
    grid.sync();

    const int mt0 = 2 * wv, mt1 = 2 * wv + 1;        // this wave's m-tiles

    // ---------- recurrence ----------
    for (int t = 0; ; ++t) {
        // ===== phase A: [out | mh] = h @ [W_out | W_r] =====
        if (t < TSTEPS || b < 64) {
            float4v aH0 = {0.f,0.f,0.f,0.f}, aX0 = {0.f,0.f,0.f,0.f};
            float4v aH1 = {0.f,0.f,0.f,0.f}, aX1 = {0.f,0.f,0.f,0.f};
            const half8* AH = (const half8*)hH;
            const half8* AL = (const half8*)hL;
#pragma unroll 4
            for (int kt = 0; kt < 32; ++kt) {
                const half8 bh = *(const half8*)&WAh[kt * 512 + lane * 8];
                const half8 bl = *(const half8*)&WAl[kt * 512 + lane * 8];
                const half8 a0h = AH[(mt0 * 32 + kt) * 64 + lane];
                const half8 a0l = AL[(mt0 * 32 + kt) * 64 + lane];
                const half8 a1h = AH[(mt1 * 32 + kt) * 64 + lane];
                const half8 a1l = AL[(mt1 * 32 + kt) * 64 + lane];
                aH0 = __builtin_amdgcn_mfma_f32_16x16x32_f16(a0h, bh, aH0, 0, 0, 0);
                aX0 = __builtin_amdgcn_mfma_f32_16x16x32_f16(a0l, bh, aX0, 0, 0, 0);
                aX0 = __builtin_amdgcn_mfma_f32_16x16x32_f16(a0h, bl, aX0, 0, 0, 0);
                aH1 = __builtin_amdgcn_mfma_f32_16x16x32_f16(a1h, bh, aH1, 0, 0, 0);
                aX1 = __builtin_amdgcn_mfma_f32_16x16x32_f16(a1l, bh, aX1, 0, 0, 0);
                aX1 = __builtin_amdgcn_mfma_f32_16x16x32_f16(a1h, bl, aX1, 0, 0, 0);
            }
#pragma unroll
            for (int m = 0; m < 2; ++m) {
                const int mt = (m == 0) ? mt0 : mt1;
#pragma unroll
                for (int r = 0; r < 4; ++r) {
                    const int row = mt * 16 + kq * 4 + r;
                    float v = ((m == 0) ? aH0[r] + aX0[r] * RINV
                                        : aH1[r] + aX1[r] * RINV) + bA;
                    if (b < 64) {
                        v = fmaxf(v, 0.0f);
                        if (t < TSTEPS)
                            split16(v, &oH[frag_idx(row, cA)], &oL[frag_idx(row, cA)]);
                        if (t >= 1)
                            dout[(size_t)row * (TSTEPS * HDIM) + (size_t)(t - 1) * HDIM + cA] = v;
                    } else {
                        mh[(size_t)row * TH3 + (cA - 1024)] = v;
                    }
                }
            }
        }
        if (t == TSTEPS) break;
        grid.sync();

        // ===== phase B: mx = out @ W_k  + fused GRU gates -> h planes =====
        {
            float4v aH0 = {0.f,0.f,0.f,0.f}, aX0 = {0.f,0.f,0.f,0.f};
            float4v aH1 = {0.f,0.f,0.f,0.f}, aX1 = {0.f,0.f,0.f,0.f};
            const half8* AH = (const half8*)oH;
            const half8* AL = (const half8*)oL;
#pragma unroll 4
            for (int kt = 0; kt < 32; ++kt) {
                const half8 bh = *(const half8*)&WBh[kt * 512 + lane * 8];
                const half8 bl = *(const half8*)&WBl[kt * 512 + lane * 8];
                const half8 a0h = AH[(mt0 * 32 + kt) * 64 + lane];
                const half8 a0l = AL[(mt0 * 32 + kt) * 64 + lane];
                const half8 a1h = AH[(mt1 * 32 + kt) * 64 + lane];
                const half8 a1l = AL[(mt1 * 32 + kt) * 64 + lane];
                aH0 = __builtin_amdgcn_mfma_f32_16x16x32_f16(a0h, bh, aH0, 0, 0, 0);
                aX0 = __builtin_amdgcn_mfma_f32_16x16x32_f16(a0l, bh, aX0, 0, 0, 0);
                aX0 = __builtin_amdgcn_mfma_f32_16x16x32_f16(a0h, bl, aX0, 0, 0, 0);
                aH1 = __builtin_amdgcn_mfma_f32_16x16x32_f16(a1h, bh, aH1, 0, 0, 0);
                aX1 = __builtin_amdgcn_mfma_f32_16x16x32_f16(a1l, bh, aX1, 0, 0, 0);
                aX1 = __builtin_amdgcn_mfma_f32_16x16x32_f16(a1h, bl, aX1, 0, 0, 0);
            }
            // per-lane mx values (col nn), bias folded
            float vals[2][4], v1[2][4], v2[2][4];
#pragma unroll
            for (int r = 0; r < 4; ++r) {
                vals[0][r] = aH0[r] + aX0[r] * RINV + bB;
                vals[1][r] = aH1[r] + aX1[r] * RINV + bB;
            }
            // gather r-gate (col+1) and h-gate (col+2) values to z-lanes
#pragma unroll
            for (int m = 0; m < 2; ++m)
#pragma unroll
                for (int r = 0; r < 4; ++r) {
                    v1[m][r] = __shfl(vals[m][r], (lane + 1) & 63);
                    v2[m][r] = __shfl(vals[m][r], (lane + 2) & 63);
                }
            if (nn < 12 && (nn % 3) == 0) {
                const int j = 4 * b + nn / 3;
#pragma unroll
                for (int m = 0; m < 2; ++m) {
                    const int mt = (m == 0) ? mt0 : mt1;
#pragma unroll
                    for (int r = 0; r < 4; ++r) {
                        const int row = mt * 16 + kq * 4 + r;
                        const float* mhr = mh + (size_t)row * TH3;
                        const float z    = sigmoidf_(vals[m][r] + mhr[j]);
                        const float rg   = sigmoidf_(v1[m][r] + mhr[1024 + j]);
                        const float cand = tanhf(v2[m][r] + rg * mhr[2048 + j]);
                        const int fi = frag_idx(row, j);
                        const float hp = (float)hH[fi] + (float)hL[fi] * RINV;
                        const float hn = z * hp + (1.0f - z) * cand;
                        split16(hn, &hH[fi], &hL[fi]);
                    }
                }
            }
        }
        grid.sync();
    }
}

// ===========================================================================
// Fallback path (round-2 kernels) — used only if cooperative launch fails.
// ===========================================================================
__global__ __launch_bounds__(128) void gemmA(
    const float* __restrict__ A,
    const float* __restrict__ W0, const float* __restrict__ b0, int act0,
    float* __restrict__ C0, float* __restrict__ C2,
    const float* __restrict__ W1, const float* __restrict__ b1,
    float* __restrict__ C1)
{
    __shared__ __align__(16) float Ass[32][36];
    __shared__ __align__(16) float Ws[32][68];
    const int tid = threadIdx.x;
    const int bx = blockIdx.x, by = blockIdx.y;
    const int r0 = by * 32;
    const bool reg0 = (bx < 16);
    const int c0 = reg0 ? bx * 64 : (bx - 16) * 64;
    const float* __restrict__ W = reg0 ? W0 : W1;
    const int ldw = reg0 ? 1024 : 3072;
    const int arow = tid >> 2;
    const int ak   = (tid & 3) << 2;
    const int wrow = tid >> 4;
    const int wcol = (tid & 15) << 2;
    const int ty = tid >> 4;
    const int tx = tid & 15;
    float acc[4][4] = {};
    const float* Ap = A + (size_t)(r0 + arow) * 1024 + ak;
    const float* Wp = W + (size_t)wrow * ldw + c0 + wcol;
    for (int k0 = 0; k0 < 1024; k0 += 32) {
        const float4 a0 = *(const float4*)(Ap + k0);
        const float4 a1 = *(const float4*)(Ap + k0 + 16);
        const float4 w0 = *(const float4*)(Wp + (size_t)k0 * ldw);
        const float4 w1 = *(const float4*)(Wp + (size_t)(k0 + 8) * ldw);
        const float4 w2 = *(const float4*)(Wp + (size_t)(k0 + 16) * ldw);
        const float4 w3 = *(const float4*)(Wp + (size_t)(k0 + 24) * ldw);
        __syncthreads();
        Ass[ak + 0][arow] = a0.x; Ass[ak + 1][arow] = a0.y;
        Ass[ak + 2][arow] = a0.z; Ass[ak + 3][arow] = a0.w;
        Ass[ak + 16][arow] = a1.x; Ass[ak + 17][arow] = a1.y;
        Ass[ak + 18][arow] = a1.z; Ass[ak + 19][arow] = a1.w;
        *(float4*)&Ws[wrow][wcol]      = w0;
        *(float4*)&Ws[wrow + 8][wcol]  = w1;
        *(float4*)&Ws[wrow + 16][wcol] = w2;
        *(float4*)&Ws[wrow + 24][wcol] = w3;
        __syncthreads();
#pragma unroll
        for (int kk = 0; kk < 32; ++kk) {
            const float4 a4 = *(const float4*)&Ass[kk][ty << 2];
            const float4 w4 = *(const float4*)&Ws[kk][tx << 2];
            const float a[4] = {a4.x, a4.y, a4.z, a4.w};
            const float w[4] = {w4.x, w4.y, w4.z, w4.w};
#pragma unroll
            for (int i = 0; i < 4; ++i)
#pragma unroll
                for (int j = 0; j < 4; ++j)
                    acc[i][j] = fmaf(a[i], w[j], acc[i][j]);
        }
    }
    const float* bias = reg0 ? b0 : b1;
    const float4 bv = *(const float4*)(bias + c0 + (tx << 2));
    const float bb[4] = {bv.x, bv.y, bv.z, bv.w};
#pragma unroll
    for (int i = 0; i < 4; ++i) {
        const int row = r0 + (ty << 2) + i;
        float v[4];
#pragma unroll
        for (int j = 0; j < 4; ++j) {
            float tv = acc[i][j] + bb[j];
            if (reg0) { tv = (act0 == 1) ? fmaxf(tv, 0.0f) : tanhf(tv); }
            v[j] = tv;
        }
        const float4 o = make_float4(v[0], v[1], v[2], v[3]);
        if (reg0) {
            *(float4*)(C0 + (size_t)row * 1024 + c0 + (tx << 2)) = o;
            if (C2)
                *(float4*)(C2 + (size_t)row * (TSTEPS * HDIM) + c0 + (tx << 2)) = o;
        } else {
            *(float4*)(C1 + (size_t)row * TH3 + c0 + (tx << 2)) = o;
        }
    }
}

__global__ __launch_bounds__(128) void gemmB(
    const float* __restrict__ A,
    const float* __restrict__ Wk,
    const float* __restrict__ bg,
    const float* __restrict__ mh,
    float* __restrict__ h)
{
    __shared__ __align__(16) float Ass[32][36];
    __shared__ __align__(16) float Ws[3][32][20];
    const int tid = threadIdx.x;
    const int j0 = blockIdx.x * 16;
    const int r0 = blockIdx.y * 32;
    const int arow = tid >> 2;
    const int ak   = (tid & 3) << 2;
    const int wr   = tid >> 2;
    const int wc   = (tid & 3) << 2;
    const int ty = tid >> 4;
    const int tx = tid & 15;
    float acc[3][4] = {};
    const float* Ap = A + (size_t)(r0 + arow) * 1024 + ak;
    const float* Wp = Wk + (size_t)wr * TH3 + j0 + wc;
    for (int k0 = 0; k0 < 1024; k0 += 32) {
        const float4 a0 = *(const float4*)(Ap + k0);
        const float4 a1 = *(const float4*)(Ap + k0 + 16);
        float4 wv[3];
#pragma unroll
        for (int c = 0; c < 3; ++c)
            wv[c] = *(const float4*)(Wp + (size_t)k0 * TH3 + c * 1024);
        __syncthreads();
        Ass[ak + 0][arow] = a0.x; Ass[ak + 1][arow] = a0.y;
        Ass[ak + 2][arow] = a0.z; Ass[ak + 3][arow] = a0.w;
        Ass[ak + 16][arow] = a1.x; Ass[ak + 17][arow] = a1.y;
        Ass[ak + 18][arow] = a1.z; Ass[ak + 19][arow] = a1.w;
#pragma unroll
        for (int c = 0; c < 3; ++c)
            *(float4*)&Ws[c][wr][wc] = wv[c];
        __syncthreads();
#pragma unroll
        for (int kk = 0; kk < 32; ++kk) {
            const float4 a4 = *(const float4*)&Ass[kk][ty << 2];
            const float a[4] = {a4.x, a4.y, a4.z, a4.w};
            const float wz = Ws[0][kk][tx];
            const float wr_ = Ws[1][kk][tx];
            const float wh = Ws[2][kk][tx];
#pragma unroll
            for (int i = 0; i < 4; ++i) {
                acc[0][i] = fmaf(a[i], wz, acc[0][i]);
                acc[1][i] = fmaf(a[i], wr_, acc[1][i]);
                acc[2][i] = fmaf(a[i], wh, acc[2][i]);
            }
        }
    }
    const int j = j0 + tx;
    const float bz = bg[j];
    const float br = bg[HDIM + j];
    const float bh = bg[2 * HDIM + j];
#pragma unroll
    for (int i = 0; i < 4; ++i) {
        const int row = r0 + (ty << 2) + i;
        const float* mhp = mh + (size_t)row * TH3;
        const float z  = sigmoidf_(acc[0][i] + bz + mhp[j]);
        const float rg = sigmoidf_(acc[1][i] + br + mhp[HDIM + j]);
        const float cand = tanhf(acc[2][i] + bh + rg * mhp[2 * HDIM + j]);
        const size_t hi = (size_t)row * HDIM + j;
        const float ho = h[hi];
        h[hi] = z * ho + (1.0f - z) * cand;
    }
}

extern "C" void kernel_launch(void* const* d_in, const int* in_sizes, int n_in,
                              void* d_out, int out_size, void* d_ws, size_t ws_size,
                              hipStream_t stream) {
    const float* x     = (const float*)d_in[0];
    const float* W_fs  = (const float*)d_in[1];
    const float* b_fs  = (const float*)d_in[2];
    const float* W_out = (const float*)d_in[3];
    const float* b_out = (const float*)d_in[4];
    const float* W_k   = (const float*)d_in[5];
    const float* W_r   = (const float*)d_in[6];
    const float* b_gru = (const float*)d_in[7];
    float* out = (float*)d_out;            // [B, T, H]

    char* ws = (char*)d_ws;
    _Float16* hH = (_Float16*)(ws);                  // 512KB each plane
    _Float16* hL = (_Float16*)(ws + 512 * 1024);
    _Float16* oH = (_Float16*)(ws + 1024 * 1024);
    _Float16* oL = (_Float16*)(ws + 1536 * 1024);
    float*    mh = (float*)   (ws + 2048 * 1024);    // 3MB

    void* args[] = {
        (void*)&x, (void*)&W_fs, (void*)&b_fs, (void*)&W_out, (void*)&b_out,
        (void*)&W_k, (void*)&W_r, (void*)&b_gru, (void*)&out,
        (void*)&hH, (void*)&hL, (void*)&oH, (void*)&oL, (void*)&mh
    };
    const size_t lds_bytes = 65536 * sizeof(_Float16);   // 128KB
    hipError_t err = hipLaunchCooperativeKernel(
        (const void*)decoder_mfma, dim3(256), dim3(512),
        args, lds_bytes, stream);

    if (err != hipSuccess) {
        // fallback: round-2 multi-launch fp32 path
        float* h    = (float*)d_ws;
        float* outb = h    + BROWS * HDIM;
        float* mhf  = outb + BROWS * HDIM;
        const dim3 blk(128);
        const dim3 gridInit(16, 8);
        const dim3 gridA(64, 8);
        const dim3 gridB(64, 8);
        gemmA<<<gridInit, blk, 0, stream>>>(x, W_fs, b_fs, 2, h, nullptr,
                                            nullptr, nullptr, nullptr);
        for (int t = 0; t < TSTEPS; ++t) {
            float* c2 = (t >= 1) ? (out + (size_t)(t - 1) * HDIM) : nullptr;
            gemmA<<<gridA, blk, 0, stream>>>(h, W_out, b_out, 1, outb, c2,
                                             W_r, b_gru + TH3, mhf);
            gemmB<<<gridB, blk, 0, stream>>>(outb, W_k, b_gru, mhf, h);
        }
        gemmA<<<gridInit, blk, 0, stream>>>(h, W_out, b_out, 1, outb,
                                            out + (size_t)(TSTEPS - 1) * HDIM,
                                            nullptr, nullptr, nullptr);
    }
}